// Round 1
// baseline (151.643 us; speedup 1.0000x reference)
//
#include <hip/hip_runtime.h>
#include <math.h>

#define NB    2
#define NPTS  65536
#define NVSUB 689
#define NJ    24
#define GR    64
#define GRV   (GR*GR*GR)          // 262144 voxels
#define THRESH2 0.0144f           // 0.12^2

// output layout (floats): pts_cano [B,N,1,3] | mask [B,N,1] | w_tf [B,N,4,4]
#define O_PTS  0
#define O_MASK (NB*NPTS*3)        // 393216
#define O_WTF  (O_MASK + NB*NPTS) // 524288

// ---------------- kernel 1: [24][64^3] -> [64^3][24] transpose ----------------
__global__ __launch_bounds__(256) void transpose_grid(const float* __restrict__ g,
                                                      float* __restrict__ gt) {
    int vox = blockIdx.x * 256 + threadIdx.x;
    float v[NJ];
#pragma unroll
    for (int c = 0; c < NJ; ++c) v[c] = g[c * GRV + vox];   // coalesced per c
    float4* dst = (float4*)(gt + (size_t)vox * NJ);
#pragma unroll
    for (int c4 = 0; c4 < 6; ++c4)
        dst[c4] = make_float4(v[4*c4+0], v[4*c4+1], v[4*c4+2], v[4*c4+3]);
}

// ---------------- main fused kernel ----------------
template <bool TRANSPOSED>
__device__ inline void process_point(int b, int n, float qx, float qy, float qz,
                                     float dist2,
                                     const float* __restrict__ grid,
                                     const float* __restrict__ s_tfs,
                                     float gsx, float gsy, float gsz,
                                     float gox, float goy, float goz,
                                     float* __restrict__ out) {
    // normalize + clip to [-1,1]
    float cx = fminf(fmaxf((qx - gox) * gsx, -1.f), 1.f);
    float cy = fminf(fmaxf((qy - goy) * gsy, -1.f), 1.f);
    float cz = fminf(fmaxf((qz - goz) * gsz, -1.f), 1.f);
    float x = (cx + 1.f) * 0.5f * (GR - 1);
    float y = (cy + 1.f) * 0.5f * (GR - 1);
    float z = (cz + 1.f) * 0.5f * (GR - 1);
    int x0 = (int)floorf(x), y0 = (int)floorf(y), z0 = (int)floorf(z);
    int x1 = min(x0 + 1, GR - 1), y1 = min(y0 + 1, GR - 1), z1 = min(z0 + 1, GR - 1);
    float fx = x - (float)x0, fy = y - (float)y0, fz = z - (float)z0;
    float wx[2] = {1.f - fx, fx}, wy[2] = {1.f - fy, fy}, wz[2] = {1.f - fz, fz};

    float w[NJ];
#pragma unroll
    for (int c = 0; c < NJ; ++c) w[c] = 0.f;

#pragma unroll
    for (int ci = 0; ci < 8; ++ci) {
        int xi = (ci & 1) ? x1 : x0;
        int yi = (ci & 2) ? y1 : y0;
        int zi = (ci & 4) ? z1 : z0;
        float wt = wx[ci & 1] * wy[(ci >> 1) & 1] * wz[(ci >> 2) & 1];
        int vox = (zi * GR + yi) * GR + xi;
        if (TRANSPOSED) {
            const float4* g4 = (const float4*)(grid + (size_t)vox * NJ);
#pragma unroll
            for (int c4 = 0; c4 < 6; ++c4) {
                float4 gv = g4[c4];
                w[4*c4+0] = fmaf(wt, gv.x, w[4*c4+0]);
                w[4*c4+1] = fmaf(wt, gv.y, w[4*c4+1]);
                w[4*c4+2] = fmaf(wt, gv.z, w[4*c4+2]);
                w[4*c4+3] = fmaf(wt, gv.w, w[4*c4+3]);
            }
        } else {
#pragma unroll
            for (int c = 0; c < NJ; ++c)
                w[c] = fmaf(wt, grid[c * GRV + vox], w[c]);
        }
    }
    float s = 0.f;
#pragma unroll
    for (int c = 0; c < NJ; ++c) s += w[c];
    float inv = 1.f / fmaxf(s, 1e-6f);

    float acc[16];
#pragma unroll
    for (int k = 0; k < 16; ++k) acc[k] = 0.f;
    const float* tb = s_tfs + b * NJ * 16;
#pragma unroll
    for (int j = 0; j < NJ; ++j) {
        float wj = w[j] * inv;
#pragma unroll
        for (int k = 0; k < 16; ++k) acc[k] = fmaf(wj, tb[j * 16 + k], acc[k]);
    }

    float px = acc[0] * qx + acc[1] * qy + acc[2]  * qz + acc[3];
    float py = acc[4] * qx + acc[5] * qy + acc[6]  * qz + acc[7];
    float pz = acc[8] * qx + acc[9] * qy + acc[10] * qz + acc[11];

    size_t bn = (size_t)b * NPTS + n;
    out[O_PTS + bn * 3 + 0] = px;
    out[O_PTS + bn * 3 + 1] = py;
    out[O_PTS + bn * 3 + 2] = pz;
    out[O_MASK + bn] = (dist2 < THRESH2) ? 1.f : 0.f;
    float4* wt4 = (float4*)(out + O_WTF + bn * 16);
    wt4[0] = make_float4(acc[0],  acc[1],  acc[2],  acc[3]);
    wt4[1] = make_float4(acc[4],  acc[5],  acc[6],  acc[7]);
    wt4[2] = make_float4(acc[8],  acc[9],  acc[10], acc[11]);
    wt4[3] = make_float4(acc[12], acc[13], acc[14], acc[15]);
}

template <bool TRANSPOSED>
__global__ __launch_bounds__(256) void snarf_main(
    const float* __restrict__ pts_in,    // [2,N,3]
    const float* __restrict__ vs,        // [689,3]
    const float* __restrict__ shape_off, // [6890,3]
    const int*   __restrict__ init_idx,  // [N,3]
    const float* __restrict__ init_bar,  // [N,3]
    const float* __restrict__ grid,      // transposed [64^3][24] or raw [24][64^3]
    const float* __restrict__ tfs,       // [2,24,4,4]
    const float* __restrict__ gscale,    // [3]
    const float* __restrict__ goff,      // [3]
    float* __restrict__ out) {
    __shared__ float4 s_vs[NVSUB];
    __shared__ float  s_tfs[NB * NJ * 16];
    const int tid = threadIdx.x;
    for (int i = tid; i < NVSUB; i += 256) {
        float x = vs[i * 3 + 0], y = vs[i * 3 + 1], z = vs[i * 3 + 2];
        s_vs[i] = make_float4(x, y, z, x * x + y * y + z * z);
    }
    for (int i = tid; i < NB * NJ * 16; i += 256) s_tfs[i] = tfs[i];
    __syncthreads();

    const int n = blockIdx.x * 256 + tid;

    float p0x = pts_in[n * 3 + 0], p0y = pts_in[n * 3 + 1], p0z = pts_in[n * 3 + 2];
    float p1x = pts_in[(NPTS + n) * 3 + 0], p1y = pts_in[(NPTS + n) * 3 + 1],
          p1z = pts_in[(NPTS + n) * 3 + 2];
    float pp0 = p0x * p0x + p0y * p0y + p0z * p0z;
    float pp1 = p1x * p1x + p1y * p1y + p1z * p1z;

    // ---- KNN (K=1): d2 = |p|^2 + min_v(|v|^2 - 2 p.v) ----
    float m0 = 3.4e38f, m1 = 3.4e38f;
#pragma unroll 4
    for (int v = 0; v < NVSUB; ++v) {
        float4 t = s_vs[v];   // broadcast across wave
        float d0 = p0x * t.x + p0y * t.y + p0z * t.z;
        float d1 = p1x * t.x + p1y * t.y + p1z * t.z;
        m0 = fminf(m0, fmaf(-2.f, d0, t.w));
        m1 = fminf(m1, fmaf(-2.f, d1, t.w));
    }
    float dist2_0 = m0 + pp0;
    float dist2_1 = m1 + pp1;

    // ---- barycentric shape offset (b-independent) ----
    int i0 = init_idx[n * 3 + 0] * 3;
    int i1 = init_idx[n * 3 + 1] * 3;
    int i2 = init_idx[n * 3 + 2] * 3;
    float b0 = init_bar[n * 3 + 0], b1 = init_bar[n * 3 + 1], b2 = init_bar[n * 3 + 2];
    float ox = b0 * shape_off[i0 + 0] + b1 * shape_off[i1 + 0] + b2 * shape_off[i2 + 0];
    float oy = b0 * shape_off[i0 + 1] + b1 * shape_off[i1 + 1] + b2 * shape_off[i2 + 1];
    float oz = b0 * shape_off[i0 + 2] + b1 * shape_off[i1 + 2] + b2 * shape_off[i2 + 2];

    float gsx = gscale[0], gsy = gscale[1], gsz = gscale[2];
    float gox = goff[0],   goy = goff[1],   goz = goff[2];

    process_point<TRANSPOSED>(0, n, p0x + ox, p0y + oy, p0z + oz, dist2_0,
                              grid, s_tfs, gsx, gsy, gsz, gox, goy, goz, out);
    process_point<TRANSPOSED>(1, n, p1x + ox, p1y + oy, p1z + oz, dist2_1,
                              grid, s_tfs, gsx, gsy, gsz, gox, goy, goz, out);
}

extern "C" void kernel_launch(void* const* d_in, const int* in_sizes, int n_in,
                              void* d_out, int out_size, void* d_ws, size_t ws_size,
                              hipStream_t stream) {
    const float* pts_in    = (const float*)d_in[0];
    const float* vs        = (const float*)d_in[1];
    const float* shape_off = (const float*)d_in[2];
    const int*   init_idx  = (const int*)d_in[3];
    const float* init_bar  = (const float*)d_in[4];
    const float* lbs       = (const float*)d_in[5];
    const float* tfs       = (const float*)d_in[6];
    const float* gs        = (const float*)d_in[7];
    const float* go        = (const float*)d_in[8];
    float* out = (float*)d_out;

    const size_t needed = (size_t)GRV * NJ * sizeof(float);  // ~25.2 MB
    if (ws_size >= needed) {
        float* gT = (float*)d_ws;
        transpose_grid<<<GRV / 256, 256, 0, stream>>>(lbs, gT);
        snarf_main<true><<<NPTS / 256, 256, 0, stream>>>(
            pts_in, vs, shape_off, init_idx, init_bar, gT, tfs, gs, go, out);
    } else {
        snarf_main<false><<<NPTS / 256, 256, 0, stream>>>(
            pts_in, vs, shape_off, init_idx, init_bar, lbs, tfs, gs, go, out);
    }
}

// Round 2
// 132.174 us; speedup vs baseline: 1.1473x; 1.1473x over previous
//
#include <hip/hip_runtime.h>
#include <math.h>

#define NB    2
#define NPTS  65536
#define NVSUB 689
#define NJ    24
#define GR    64
#define GRV   (GR*GR*GR)          // 262144 voxels
#define THRESH2 0.0144f           // 0.12^2

// output layout (floats): pts_cano [B,N,1,3] | mask [B,N,1] | w_tf [B,N,4,4]
#define O_PTS  0
#define O_MASK (NB*NPTS*3)        // 393216
#define O_WTF  (O_MASK + NB*NPTS) // 524288

// ---------------- kernel 1: [24][64^3] -> [64^3][24] transpose ----------------
__global__ __launch_bounds__(256) void transpose_grid(const float* __restrict__ g,
                                                      float* __restrict__ gt) {
    int vox = blockIdx.x * 256 + threadIdx.x;
    float v[NJ];
#pragma unroll
    for (int c = 0; c < NJ; ++c) v[c] = g[c * GRV + vox];   // coalesced per c
    float4* dst = (float4*)(gt + (size_t)vox * NJ);
#pragma unroll
    for (int c4 = 0; c4 < 6; ++c4)
        dst[c4] = make_float4(v[4*c4+0], v[4*c4+1], v[4*c4+2], v[4*c4+3]);
}

// ---------------- trilinear + skinning for one (b,n) point ----------------
template <bool TRANSPOSED>
__device__ inline void process_point(int b, int n, float qx, float qy, float qz,
                                     float dist2,
                                     const float* __restrict__ grid,
                                     const float* __restrict__ s_tfs,
                                     float gsx, float gsy, float gsz,
                                     float gox, float goy, float goz,
                                     float* __restrict__ out) {
    float cx = fminf(fmaxf((qx - gox) * gsx, -1.f), 1.f);
    float cy = fminf(fmaxf((qy - goy) * gsy, -1.f), 1.f);
    float cz = fminf(fmaxf((qz - goz) * gsz, -1.f), 1.f);
    float x = (cx + 1.f) * 0.5f * (GR - 1);
    float y = (cy + 1.f) * 0.5f * (GR - 1);
    float z = (cz + 1.f) * 0.5f * (GR - 1);
    int x0 = (int)floorf(x), y0 = (int)floorf(y), z0 = (int)floorf(z);
    int x1 = min(x0 + 1, GR - 1), y1 = min(y0 + 1, GR - 1), z1 = min(z0 + 1, GR - 1);
    float fx = x - (float)x0, fy = y - (float)y0, fz = z - (float)z0;
    float wx[2] = {1.f - fx, fx}, wy[2] = {1.f - fy, fy}, wz[2] = {1.f - fz, fz};

    float w[NJ];
#pragma unroll
    for (int c = 0; c < NJ; ++c) w[c] = 0.f;

#pragma unroll
    for (int ci = 0; ci < 8; ++ci) {
        int xi = (ci & 1) ? x1 : x0;
        int yi = (ci & 2) ? y1 : y0;
        int zi = (ci & 4) ? z1 : z0;
        float wt = wx[ci & 1] * wy[(ci >> 1) & 1] * wz[(ci >> 2) & 1];
        int vox = (zi * GR + yi) * GR + xi;
        if (TRANSPOSED) {
            const float4* g4 = (const float4*)(grid + (size_t)vox * NJ);
#pragma unroll
            for (int c4 = 0; c4 < 6; ++c4) {
                float4 gv = g4[c4];
                w[4*c4+0] = fmaf(wt, gv.x, w[4*c4+0]);
                w[4*c4+1] = fmaf(wt, gv.y, w[4*c4+1]);
                w[4*c4+2] = fmaf(wt, gv.z, w[4*c4+2]);
                w[4*c4+3] = fmaf(wt, gv.w, w[4*c4+3]);
            }
        } else {
#pragma unroll
            for (int c = 0; c < NJ; ++c)
                w[c] = fmaf(wt, grid[c * GRV + vox], w[c]);
        }
    }
    float s = 0.f;
#pragma unroll
    for (int c = 0; c < NJ; ++c) s += w[c];
    float inv = __builtin_amdgcn_rcpf(fmaxf(s, 1e-6f));

    float acc[16];
#pragma unroll
    for (int k = 0; k < 16; ++k) acc[k] = 0.f;
    const float* tb = s_tfs + b * NJ * 16;
#pragma unroll
    for (int j = 0; j < NJ; ++j) {
        float wj = w[j] * inv;
#pragma unroll
        for (int k = 0; k < 16; ++k) acc[k] = fmaf(wj, tb[j * 16 + k], acc[k]);
    }

    float px = acc[0] * qx + acc[1] * qy + acc[2]  * qz + acc[3];
    float py = acc[4] * qx + acc[5] * qy + acc[6]  * qz + acc[7];
    float pz = acc[8] * qx + acc[9] * qy + acc[10] * qz + acc[11];

    size_t bn = (size_t)b * NPTS + n;
    out[O_PTS + bn * 3 + 0] = px;
    out[O_PTS + bn * 3 + 1] = py;
    out[O_PTS + bn * 3 + 2] = pz;
    out[O_MASK + bn] = (dist2 < THRESH2) ? 1.f : 0.f;
    float4* wt4 = (float4*)(out + O_WTF + bn * 16);
    wt4[0] = make_float4(acc[0],  acc[1],  acc[2],  acc[3]);
    wt4[1] = make_float4(acc[4],  acc[5],  acc[6],  acc[7]);
    wt4[2] = make_float4(acc[8],  acc[9],  acc[10], acc[11]);
    wt4[3] = make_float4(acc[12], acc[13], acc[14], acc[15]);
}

// ---------------- main fused kernel ----------------
// Block = 256 threads = 4 waves. Wave q (q=0..3) handles vertex quarter q of
// the KNN for 64 points (both batches). Partial mins combined via LDS; waves
// 0/1 then do trilinear+skinning for b=0/1.  Grid = 1024 blocks -> 4 blocks/CU
// -> 16 waves/CU (50% occupancy) vs 4 waves/CU before.
template <bool TRANSPOSED>
__global__ __launch_bounds__(256, 4) void snarf_main(
    const float* __restrict__ pts_in,    // [2,N,3]
    const float* __restrict__ vs,        // [689,3]
    const float* __restrict__ shape_off, // [6890,3]
    const int*   __restrict__ init_idx,  // [N,3]
    const float* __restrict__ init_bar,  // [N,3]
    const float* __restrict__ grid,      // transposed [64^3][24] or raw [24][64^3]
    const float* __restrict__ tfs,       // [2,24,4,4]
    const float* __restrict__ gscale,    // [3]
    const float* __restrict__ goff,      // [3]
    float* __restrict__ out) {
    __shared__ float4 s_vs[NVSUB];
    __shared__ float  s_tfs[NB * NJ * 16];
    __shared__ float  s_m[NB][4][64];
    const int tid = threadIdx.x;
    const int q  = tid >> 6;     // wave id = vertex quarter
    const int nl = tid & 63;
    const int n = blockIdx.x * 64 + nl;

    for (int i = tid; i < NVSUB; i += 256) {
        float x = vs[i * 3 + 0], y = vs[i * 3 + 1], z = vs[i * 3 + 2];
        s_vs[i] = make_float4(x, y, z, x * x + y * y + z * z);
    }
    for (int i = tid; i < NB * NJ * 16; i += 256) s_tfs[i] = tfs[i];
    __syncthreads();

    const float p0x = pts_in[n * 3 + 0], p0y = pts_in[n * 3 + 1], p0z = pts_in[n * 3 + 2];
    const float p1x = pts_in[(NPTS + n) * 3 + 0], p1y = pts_in[(NPTS + n) * 3 + 1],
                p1z = pts_in[(NPTS + n) * 3 + 2];

    // ---- KNN over this wave's vertex quarter: d2 = |p|^2 + min(|v|^2 - 2 p.v)
    // 4 independent min-chains (2 batches x unroll-2) for ILP.
    const int vbeg = q * 173;
    const int vend = min(vbeg + 173, NVSUB);
    float m0a = 3.4e38f, m0b = 3.4e38f, m1a = 3.4e38f, m1b = 3.4e38f;
    int v = vbeg;
    for (; v + 2 <= vend; v += 2) {
        float4 ta = s_vs[v];
        float4 tb = s_vs[v + 1];
        m0a = fminf(m0a, fmaf(-2.f, p0x * ta.x + p0y * ta.y + p0z * ta.z, ta.w));
        m1a = fminf(m1a, fmaf(-2.f, p1x * ta.x + p1y * ta.y + p1z * ta.z, ta.w));
        m0b = fminf(m0b, fmaf(-2.f, p0x * tb.x + p0y * tb.y + p0z * tb.z, tb.w));
        m1b = fminf(m1b, fmaf(-2.f, p1x * tb.x + p1y * tb.y + p1z * tb.z, tb.w));
    }
    if (v < vend) {
        float4 ta = s_vs[v];
        m0a = fminf(m0a, fmaf(-2.f, p0x * ta.x + p0y * ta.y + p0z * ta.z, ta.w));
        m1a = fminf(m1a, fmaf(-2.f, p1x * ta.x + p1y * ta.y + p1z * ta.z, ta.w));
    }
    s_m[0][q][nl] = fminf(m0a, m0b);
    s_m[1][q][nl] = fminf(m1a, m1b);
    __syncthreads();

    if (q < 2) {
        // combined KNN min for this batch
        float mm = fminf(fminf(s_m[q][0][nl], s_m[q][1][nl]),
                         fminf(s_m[q][2][nl], s_m[q][3][nl]));
        // barycentric shape offset (b-independent, computed by waves 0 and 1)
        int i0 = init_idx[n * 3 + 0] * 3;
        int i1 = init_idx[n * 3 + 1] * 3;
        int i2 = init_idx[n * 3 + 2] * 3;
        float b0 = init_bar[n * 3 + 0], b1 = init_bar[n * 3 + 1], b2 = init_bar[n * 3 + 2];
        float ox = b0 * shape_off[i0 + 0] + b1 * shape_off[i1 + 0] + b2 * shape_off[i2 + 0];
        float oy = b0 * shape_off[i0 + 1] + b1 * shape_off[i1 + 1] + b2 * shape_off[i2 + 1];
        float oz = b0 * shape_off[i0 + 2] + b1 * shape_off[i1 + 2] + b2 * shape_off[i2 + 2];

        float px = (q == 0) ? p0x : p1x;
        float py = (q == 0) ? p0y : p1y;
        float pz = (q == 0) ? p0z : p1z;
        float pp = px * px + py * py + pz * pz;
        float dist2 = mm + pp;

        float gsx = gscale[0], gsy = gscale[1], gsz = gscale[2];
        float gox = goff[0],   goy = goff[1],   goz = goff[2];

        process_point<TRANSPOSED>(q, n, px + ox, py + oy, pz + oz, dist2,
                                  grid, s_tfs, gsx, gsy, gsz, gox, goy, goz, out);
    }
}

extern "C" void kernel_launch(void* const* d_in, const int* in_sizes, int n_in,
                              void* d_out, int out_size, void* d_ws, size_t ws_size,
                              hipStream_t stream) {
    const float* pts_in    = (const float*)d_in[0];
    const float* vs        = (const float*)d_in[1];
    const float* shape_off = (const float*)d_in[2];
    const int*   init_idx  = (const int*)d_in[3];
    const float* init_bar  = (const float*)d_in[4];
    const float* lbs       = (const float*)d_in[5];
    const float* tfs       = (const float*)d_in[6];
    const float* gs        = (const float*)d_in[7];
    const float* go        = (const float*)d_in[8];
    float* out = (float*)d_out;

    const size_t needed = (size_t)GRV * NJ * sizeof(float);  // ~25.2 MB
    if (ws_size >= needed) {
        float* gT = (float*)d_ws;
        transpose_grid<<<GRV / 256, 256, 0, stream>>>(lbs, gT);
        snarf_main<true><<<NPTS / 64, 256, 0, stream>>>(
            pts_in, vs, shape_off, init_idx, init_bar, gT, tfs, gs, go, out);
    } else {
        snarf_main<false><<<NPTS / 64, 256, 0, stream>>>(
            pts_in, vs, shape_off, init_idx, init_bar, lbs, tfs, gs, go, out);
    }
}